// Round 1
// baseline (820.203 us; speedup 1.0000x reference)
//
#include <hip/hip_runtime.h>
#include <hip/hip_bf16.h>
#include <cstdint>
#include <cstddef>

// Problem constants (from reference)
#define M_TOTAL 16384   // WORLD_SIZE * M_LOCAL
#define K_DIM   4096
#define N_DIM   4096

typedef __attribute__((ext_vector_type(8))) short s16x8;
typedef __attribute__((ext_vector_type(4))) float f32x4;

// ---------- fp32 -> bf16 round-to-nearest-even ----------
__device__ __forceinline__ unsigned short f2bf(float x) {
  unsigned u = __float_as_uint(x);
  unsigned r = (u + 0x7fffu + ((u >> 16) & 1u)) >> 16;
  return (unsigned short)r;
}

// ---------- cast A [M,K] fp32 -> bf16, 8 elems/thread ----------
__global__ __launch_bounds__(256) void cast_kernel(const float* __restrict__ in,
                                                   unsigned short* __restrict__ out,
                                                   long n8) {
  long i = (long)blockIdx.x * 256 + threadIdx.x;
  if (i >= n8) return;
  const f32x4* p = (const f32x4*)in + i * 2;
  f32x4 a = p[0], b = p[1];
  union { s16x8 v; unsigned short u[8]; } r;
  r.u[0] = f2bf(a.x); r.u[1] = f2bf(a.y); r.u[2] = f2bf(a.z); r.u[3] = f2bf(a.w);
  r.u[4] = f2bf(b.x); r.u[5] = f2bf(b.y); r.u[6] = f2bf(b.z); r.u[7] = f2bf(b.w);
  *((s16x8*)out + i) = r.v;
}

// ---------- transpose+cast W [K,N] fp32 -> Bt [N,K] bf16 ----------
__global__ __launch_bounds__(256) void transpose_cast_kernel(const float* __restrict__ B,
                                                             unsigned short* __restrict__ Bt) {
  __shared__ float tile[64][65];
  int nbx = N_DIM / 64;
  int n0 = (blockIdx.x % nbx) * 64;
  int k0 = (blockIdx.x / nbx) * 64;
  int tx = threadIdx.x & 63;
  int ty = threadIdx.x >> 6;   // 0..3
#pragma unroll
  for (int i = 0; i < 64; i += 4)
    tile[ty + i][tx] = B[(size_t)(k0 + ty + i) * N_DIM + n0 + tx];
  __syncthreads();
#pragma unroll
  for (int i = 0; i < 64; i += 4)
    Bt[(size_t)(n0 + ty + i) * K_DIM + k0 + tx] = f2bf(tile[tx][ty + i]);
}

// ---------- bf16 MFMA GEMM: C[M,N] = A[M,K] * Bt[N,K]^T + bias ----------
// 128x128 tile, BK=32, 256 threads (4 waves, 2x2), each wave 64x64 (4x4 frags of 16x16)
#define BM 128
#define BN 128
#define BK 32
#define KT (K_DIM / BK)

__device__ __forceinline__ void load_lds16(const unsigned short* g, unsigned short* l) {
  __builtin_amdgcn_global_load_lds(
      (const __attribute__((address_space(1))) unsigned int*)g,
      (__attribute__((address_space(3))) unsigned int*)l, 16, 0, 0);
}

__global__ __launch_bounds__(256, 2)
void gemm_bf16_kernel(const unsigned short* __restrict__ A,   // [M,K] bf16
                      const unsigned short* __restrict__ Bt,  // [N,K] bf16
                      const float* __restrict__ bias,
                      float* __restrict__ C) {
  __shared__ unsigned short As[2][BM * BK];   // 8 KiB per buffer
  __shared__ unsigned short Bs[2][BN * BK];

  int nwg = gridDim.x;                 // 4096, divisible by 8 -> bijective swizzle
  int wg = blockIdx.x;
  int cpx = nwg >> 3;
  int swz = (wg & 7) * cpx + (wg >> 3);
  int nbn = N_DIM / BN;                // 32
  int bm = (swz / nbn) * BM;
  int bn = (swz % nbn) * BN;

  int tid = threadIdx.x;
  int wid = tid >> 6;                  // 0..3
  int lane = tid & 63;
  int wm = wid >> 1, wn = wid & 1;     // 2x2 wave grid

  const unsigned short* gA = A + (size_t)bm * K_DIM;
  const unsigned short* gB = Bt + (size_t)bn * K_DIM;

  f32x4 zero = {0.f, 0.f, 0.f, 0.f};
  f32x4 acc[4][4];
#pragma unroll
  for (int m = 0; m < 4; ++m)
#pragma unroll
    for (int n = 0; n < 4; ++n) acc[m][n] = zero;

  // Staging: 8 KiB per tile per operand. Linear layout [row][BK] bf16 (64 B/row).
  // issue i, wave w covers bytes [i*4096 + w*1024, +1024); lane dest = base + lane*16 (HW).
  int off0 = wid * 1024 + lane * 16;           // issue 0 byte offset
  int row0 = off0 >> 6, k0us = (off0 & 63) >> 1;
  int off1 = 4096 + wid * 1024 + lane * 16;    // issue 1
  int row1 = off1 >> 6, k1us = (off1 & 63) >> 1;
  int ldsbase0 = (wid * 1024) >> 1;            // ushort units, wave-uniform
  int ldsbase1 = (4096 + wid * 1024) >> 1;

  // prologue: stage tile 0 into buffer 0
  {
    load_lds16(gA + (size_t)row0 * K_DIM + k0us, &As[0][ldsbase0]);
    load_lds16(gB + (size_t)row0 * K_DIM + k0us, &Bs[0][ldsbase0]);
    load_lds16(gA + (size_t)row1 * K_DIM + k1us, &As[0][ldsbase1]);
    load_lds16(gB + (size_t)row1 * K_DIM + k1us, &Bs[0][ldsbase1]);
  }

  const int arow = (wm * 64 + (lane & 15)) * BK + (lane >> 4) * 8;  // ushort offset
  const int brow = (wn * 64 + (lane & 15)) * BK + (lane >> 4) * 8;

  int buf = 0;
  for (int kt = 0; kt < KT; ++kt) {
    __syncthreads();   // drains vmcnt(0): tile kt staged; also WAR fence for buf reuse
    if (kt + 1 < KT) {
      int kofs = (kt + 1) * BK;
      int b = buf ^ 1;
      load_lds16(gA + (size_t)row0 * K_DIM + kofs + k0us, &As[b][ldsbase0]);
      load_lds16(gB + (size_t)row0 * K_DIM + kofs + k0us, &Bs[b][ldsbase0]);
      load_lds16(gA + (size_t)row1 * K_DIM + kofs + k1us, &As[b][ldsbase1]);
      load_lds16(gB + (size_t)row1 * K_DIM + kofs + k1us, &Bs[b][ldsbase1]);
    }
    s16x8 af[4], bfr[4];
#pragma unroll
    for (int m = 0; m < 4; ++m)
      af[m] = *(const s16x8*)(&As[buf][arow + m * 16 * BK]);
#pragma unroll
    for (int n = 0; n < 4; ++n)
      bfr[n] = *(const s16x8*)(&Bs[buf][brow + n * 16 * BK]);
#pragma unroll
    for (int m = 0; m < 4; ++m)
#pragma unroll
      for (int n = 0; n < 4; ++n)
        acc[m][n] = __builtin_amdgcn_mfma_f32_16x16x32_bf16(af[m], bfr[n], acc[m][n], 0, 0, 0);
    buf ^= 1;
  }

  // epilogue: C/D layout col = lane&15, row = (lane>>4)*4 + j  [m89/m91 verified]
  int r0 = bm + wm * 64 + ((lane >> 4) << 2);
  int c0 = bn + wn * 64 + (lane & 15);
#pragma unroll
  for (int n = 0; n < 4; ++n) {
    int c = c0 + n * 16;
    float bv = bias[c];
#pragma unroll
    for (int m = 0; m < 4; ++m) {
      int r = r0 + m * 16;
#pragma unroll
      for (int j = 0; j < 4; ++j)
        C[(size_t)(r + j) * N_DIM + c] = acc[m][n][j] + bv;
    }
  }
}

// ---------- naive fp32 fallback (only if ws_size too small) ----------
__global__ __launch_bounds__(256)
void gemm_naive(const float* __restrict__ A, const float* __restrict__ B,
                const float* __restrict__ bias, float* __restrict__ C) {
  __shared__ float As[64][17];
  __shared__ float Bs[16][65];
  int nbn = N_DIM / 64;
  int m0 = (blockIdx.x / nbn) * 64;
  int n0 = (blockIdx.x % nbn) * 64;
  int tid = threadIdx.x;
  int tx = tid & 15, ty = tid >> 4;
  float acc[4][4] = {};
  for (int k0 = 0; k0 < K_DIM; k0 += 16) {
    __syncthreads();
#pragma unroll
    for (int e = tid * 4, i = 0; i < 4; ++i) {
      int idx = e + i;
      int r = idx >> 4, k = idx & 15;
      As[r][k] = A[(size_t)(m0 + r) * K_DIM + k0 + k];
    }
#pragma unroll
    for (int e = tid * 4, i = 0; i < 4; ++i) {
      int idx = e + i;
      int k = idx >> 6, n = idx & 63;
      Bs[k][n] = B[(size_t)(k0 + k) * N_DIM + n0 + n];
    }
    __syncthreads();
#pragma unroll
    for (int kk = 0; kk < 16; ++kk)
#pragma unroll
      for (int i = 0; i < 4; ++i)
#pragma unroll
        for (int j = 0; j < 4; ++j)
          acc[i][j] += As[ty * 4 + i][kk] * Bs[kk][tx * 4 + j];
  }
#pragma unroll
  for (int i = 0; i < 4; ++i)
#pragma unroll
    for (int j = 0; j < 4; ++j) {
      int r = m0 + ty * 4 + i, c = n0 + tx * 4 + j;
      C[(size_t)r * N_DIM + c] = acc[i][j] + bias[c];
    }
}

extern "C" void kernel_launch(void* const* d_in, const int* in_sizes, int n_in,
                              void* d_out, int out_size, void* d_ws, size_t ws_size,
                              hipStream_t stream) {
  const float* A32  = (const float*)d_in[0];   // [8, 2048, 4096] == [16384, 4096]
  const float* W32  = (const float*)d_in[1];   // [4096, 4096] (K, N)
  const float* bias = (const float*)d_in[2];   // [4096]
  float* C = (float*)d_out;

  const size_t needA = (size_t)M_TOTAL * K_DIM * sizeof(unsigned short); // 128 MiB
  const size_t needB = (size_t)N_DIM * K_DIM * sizeof(unsigned short);   // 32 MiB

  if (ws_size >= needA + needB) {
    unsigned short* Abf = (unsigned short*)d_ws;
    unsigned short* Btb = (unsigned short*)((char*)d_ws + needA);
    long n8 = (long)M_TOTAL * K_DIM / 8;
    cast_kernel<<<(int)((n8 + 255) / 256), 256, 0, stream>>>(A32, Abf, n8);
    transpose_cast_kernel<<<(K_DIM / 64) * (N_DIM / 64), 256, 0, stream>>>(W32, Btb);
    gemm_bf16_kernel<<<(M_TOTAL / BM) * (N_DIM / BN), 256, 0, stream>>>(Abf, Btb, bias, C);
  } else {
    gemm_naive<<<(M_TOTAL / 64) * (N_DIM / 64), 256, 0, stream>>>(A32, W32, bias, C);
  }
}

// Round 2
// 560.130 us; speedup vs baseline: 1.4643x; 1.4643x over previous
//
#include <hip/hip_runtime.h>
#include <hip/hip_bf16.h>
#include <cstdint>
#include <cstddef>

#define M_TOTAL 16384   // WORLD_SIZE * M_LOCAL
#define K_DIM   4096
#define N_DIM   4096

typedef __attribute__((ext_vector_type(8))) short s16x8;
typedef __attribute__((ext_vector_type(4))) float f32x4;
typedef unsigned short ushort_t;

// ---------- fp32 -> bf16 round-to-nearest-even ----------
__device__ __forceinline__ ushort_t f2bf(float x) {
  unsigned u = __float_as_uint(x);
  return (ushort_t)((u + 0x7fffu + ((u >> 16) & 1u)) >> 16);
}

// ---------- cast A [M,K] fp32 -> bf16, 8 elems/thread ----------
__global__ __launch_bounds__(256) void cast_kernel(const float* __restrict__ in,
                                                   ushort_t* __restrict__ out,
                                                   long n8) {
  long i = (long)blockIdx.x * 256 + threadIdx.x;
  if (i >= n8) return;
  const f32x4* p = (const f32x4*)in + i * 2;
  f32x4 a = p[0], b = p[1];
  union { s16x8 v; ushort_t u[8]; } r;
  r.u[0] = f2bf(a.x); r.u[1] = f2bf(a.y); r.u[2] = f2bf(a.z); r.u[3] = f2bf(a.w);
  r.u[4] = f2bf(b.x); r.u[5] = f2bf(b.y); r.u[6] = f2bf(b.z); r.u[7] = f2bf(b.w);
  *((s16x8*)out + i) = r.v;
}

// ---------- transpose+cast W [K,N] fp32 -> Bt [N,K] bf16 ----------
__global__ __launch_bounds__(256) void transpose_cast_kernel(const float* __restrict__ B,
                                                             ushort_t* __restrict__ Bt) {
  __shared__ float tile[64][65];
  int nbx = N_DIM / 64;
  int n0 = (blockIdx.x % nbx) * 64;
  int k0 = (blockIdx.x / nbx) * 64;
  int tx = threadIdx.x & 63;
  int ty = threadIdx.x >> 6;
#pragma unroll
  for (int i = 0; i < 64; i += 4)
    tile[ty + i][tx] = B[(size_t)(k0 + ty + i) * N_DIM + n0 + tx];
  __syncthreads();
#pragma unroll
  for (int i = 0; i < 64; i += 4)
    Bt[(size_t)(n0 + ty + i) * K_DIM + k0 + tx] = f2bf(tile[tx][ty + i]);
}

// ============================================================================
// 256x256 8-phase bf16 GEMM (T2 swizzle + T3/T4 counted vmcnt + T5 setprio)
// C[M,N] = A[M,K] * Bt[N,K]^T + bias
// 512 threads = 8 waves (2M x 4N); wave owns 128x64 C (8x4 frags of 16x16).
// LDS: 2 buffers x (A 32KB + B 32KB) = 128 KiB.
//   Layout per operand: 256 rows x 64 ushorts (128 B/row = 8 x 16B slots).
//   XOR swizzle: physical slot = logical slot ^ (row & 7).
//   Staged with LINEAR global_load_lds dest + inverse-swizzled global source;
//   ds_read_b128 applies the same XOR -> conflict-free (T2, rule #21).
// Stage ledger (iteration j computes tiles 2j (buf0, P1-4), 2j+1 (buf1, P5-8)):
//   P1: t(2j+1) A-half0 -> buf1   (buf1 A last read P7 of j-1: WAR ok)
//   P2: t(2j+1) A-half1 -> buf1
//   P3: t(2j+2) B-half0 -> buf0   (buf0 B last read P2: WAR ok)
//   P4: t(2j+2) B-half1 -> buf0;  vmcnt(4) drains t(2j+1) fully (leaves P3,P4)
//   P5: t(2j+2) A-half0 -> buf0   (buf0 A last read P3: WAR ok)
//   P6: t(2j+2) A-half1 -> buf0
//   P7: t(2j+3) B-half0 -> buf1   (buf1 B last read P6: WAR ok)
//   P8: t(2j+3) B-half1 -> buf1;  vmcnt(4) drains t(2j+2) fully (leaves P7,P8)
// Reads per compute-tile: Pc1: A-q0(8)+B-n0(4); Pc2: B-n1(4); Pc3: A-q1(8); Pc4: 0.
// MFMA quadrants: Pc1 acc[0..3][0..1], Pc2 acc[0..3][2..3], Pc3 acc[4..7][2..3],
//                 Pc4 acc[4..7][0..1] (b0 regs kept live from Pc1).
// ============================================================================
#define BM 256
#define BN 256
#define BK 64
#define NTILE (K_DIM / BK)   // 64 -> 32 iterations, last peeled

__device__ __forceinline__ void load_lds16(const ushort_t* g, ushort_t* l) {
  __builtin_amdgcn_global_load_lds(
      (const __attribute__((address_space(1))) unsigned int*)g,
      (__attribute__((address_space(3))) unsigned int*)l, 16, 0, 0);
}

#define BAR __builtin_amdgcn_s_barrier()
#define VMW4 asm volatile("s_waitcnt vmcnt(4)" ::: "memory")
#define VMW0 asm volatile("s_waitcnt vmcnt(0)" ::: "memory")

// stage one half-tile (2 per-wave global_load_lds): dst already includes area+wave offset
#define STAGE_A(dst, h, t) do { \
    load_lds16(pA + (size_t)((h) * 128) * K_DIM + (t) * 64, (dst) + (h) * 8192); \
    load_lds16(pA + (size_t)((h) * 128 + 64) * K_DIM + (t) * 64, (dst) + (h) * 8192 + 4096); } while (0)
#define STAGE_B(dst, h, t) do { \
    load_lds16(pB + (size_t)((h) * 128) * K_DIM + (t) * 64, (dst) + (h) * 8192); \
    load_lds16(pB + (size_t)((h) * 128 + 64) * K_DIM + (t) * 64, (dst) + (h) * 8192 + 4096); } while (0)

// ds_read_b128 fragment loads (swizzled): ks=1 flips slot bit2 -> idx ^ 32
#define READ_A(buf, arr, q) do { \
    _Pragma("unroll") for (int mf = 0; mf < 4; ++mf) { \
      int ia = aBase + ((q) * 4 + mf) * 1024; \
      arr[mf][0] = *(const s16x8*)&lds[buf][ia]; \
      arr[mf][1] = *(const s16x8*)&lds[buf][ia ^ 32]; } } while (0)
#define READ_B(buf, arr, nh) do { \
    _Pragma("unroll") for (int nf = 0; nf < 2; ++nf) { \
      int ib = bBase + ((nh) * 2 + nf) * 1024; \
      arr[nf][0] = *(const s16x8*)&lds[buf][ib]; \
      arr[nf][1] = *(const s16x8*)&lds[buf][ib ^ 32]; } } while (0)

#define MFMA_Q(arr_a, arr_b, m0, n0) do { \
    __builtin_amdgcn_s_setprio(1); \
    _Pragma("unroll") for (int mf = 0; mf < 4; ++mf) \
    _Pragma("unroll") for (int nf = 0; nf < 2; ++nf) \
    _Pragma("unroll") for (int ks = 0; ks < 2; ++ks) \
      acc[(m0) + mf][(n0) + nf] = __builtin_amdgcn_mfma_f32_16x16x32_bf16( \
          arr_a[mf][ks], arr_b[nf][ks], acc[(m0) + mf][(n0) + nf], 0, 0, 0); \
    __builtin_amdgcn_s_setprio(0); } while (0)

__global__ __launch_bounds__(512, 2)
void gemm_8phase(const ushort_t* __restrict__ A, const ushort_t* __restrict__ Bt,
                 const float* __restrict__ bias, float* __restrict__ C) {
  __shared__ ushort_t lds[2][32768];  // [buf][ A: 0..16383 | B: 16384..32767 ]

  // bijective XCD swizzle (nwg = 1024, % 8 == 0)
  int nwg = gridDim.x;
  int wg  = blockIdx.x;
  int swz = (wg & 7) * (nwg >> 3) + (wg >> 3);
  int bm = (swz >> 4) << 8;   // / 16 N-tiles * 256
  int bn = (swz & 15) << 8;

  int tid = threadIdx.x;
  int wid = tid >> 6;
  int l   = tid & 63;
  int wm = wid >> 2, wn = wid & 3;

  // staging: lane covers global (row = base + wid*8 + (l>>3), slot = (l&7)^(row&7));
  // row&7 == (l>>3)&7 for all half/quarter offsets (multiples of 8)
  int sg8 = ((l & 7) ^ ((l >> 3) & 7)) << 3;
  const ushort_t* pA = A  + (size_t)(bm + wid * 8 + (l >> 3)) * K_DIM + sg8;
  const ushort_t* pB = Bt + (size_t)(bn + wid * 8 + (l >> 3)) * K_DIM + sg8;
  ushort_t* sA0 = &lds[0][wid * 512];
  ushort_t* sA1 = &lds[1][wid * 512];
  ushort_t* sB0 = &lds[0][16384 + wid * 512];
  ushort_t* sB1 = &lds[1][16384 + wid * 512];

  // read bases: row = (wm*128 | mf*16 | (l&15)); slot = (ks*4 | (l>>4)) ^ (l&7)
  int slot0 = (l >> 4) ^ (l & 7);
  int aBase = (wm * 128 + (l & 15)) * 64 + slot0 * 8;
  int bBase = 16384 + (wn * 64 + (l & 15)) * 64 + slot0 * 8;

  f32x4 acc[8][4];
#pragma unroll
  for (int mf = 0; mf < 8; ++mf)
#pragma unroll
    for (int nf = 0; nf < 4; ++nf) acc[mf][nf] = (f32x4){0.f, 0.f, 0.f, 0.f};

  s16x8 a[4][2], b0[2][2], b1[2][2];

  // prologue: tile0 full (8 issues), tile1 B halves (4 issues); drain tile0
  STAGE_B(sB0, 0, 0); STAGE_B(sB0, 1, 0);
  STAGE_A(sA0, 0, 0); STAGE_A(sA0, 1, 0);
  STAGE_B(sB1, 0, 1); STAGE_B(sB1, 1, 1);
  VMW4; BAR;

  for (int j = 0; j < NTILE / 2 - 1; ++j) {   // j = 0..30, tiles 0..61
    int t1 = 2 * j + 1, t2 = 2 * j + 2, t3 = 2 * j + 3;
    // P1
    READ_A(0, a, 0); READ_B(0, b0, 0);
    STAGE_A(sA1, 0, t1);
    BAR; MFMA_Q(a, b0, 0, 0); BAR;
    // P2
    READ_B(0, b1, 1);
    STAGE_A(sA1, 1, t1);
    BAR; MFMA_Q(a, b1, 0, 2); BAR;
    // P3
    READ_A(0, a, 1);
    STAGE_B(sB0, 0, t2);
    BAR; MFMA_Q(a, b1, 4, 2); BAR;
    // P4
    STAGE_B(sB0, 1, t2);
    VMW4;
    BAR; MFMA_Q(a, b0, 4, 0); BAR;
    // P5
    READ_A(1, a, 0); READ_B(1, b0, 0);
    STAGE_A(sA0, 0, t2);
    BAR; MFMA_Q(a, b0, 0, 0); BAR;
    // P6
    READ_B(1, b1, 1);
    STAGE_A(sA0, 1, t2);
    BAR; MFMA_Q(a, b1, 0, 2); BAR;
    // P7
    READ_A(1, a, 1);
    STAGE_B(sB1, 0, t3);
    BAR; MFMA_Q(a, b1, 4, 2); BAR;
    // P8
    STAGE_B(sB1, 1, t3);
    VMW4;
    BAR; MFMA_Q(a, b0, 4, 0); BAR;
  }

  // tail: tiles 62 (buf0), 63 (buf1); t63 A still staged at P1,P2
  {
    READ_A(0, a, 0); READ_B(0, b0, 0);
    STAGE_A(sA1, 0, 63);
    BAR; MFMA_Q(a, b0, 0, 0); BAR;

    READ_B(0, b1, 1);
    STAGE_A(sA1, 1, 63);
    BAR; MFMA_Q(a, b1, 0, 2); BAR;

    READ_A(0, a, 1);
    BAR; MFMA_Q(a, b1, 4, 2); BAR;

    VMW0;   // epilogue drain: t63 A+B fully landed
    BAR; MFMA_Q(a, b0, 4, 0); BAR;

    READ_A(1, a, 0); READ_B(1, b0, 0);
    BAR; MFMA_Q(a, b0, 0, 0); BAR;

    READ_B(1, b1, 1);
    BAR; MFMA_Q(a, b1, 0, 2); BAR;

    READ_A(1, a, 1);
    BAR; MFMA_Q(a, b1, 4, 2); BAR;

    BAR; MFMA_Q(a, b0, 4, 0);
  }

  // epilogue: C/D layout col = lane&15, row = (lane>>4)*4 + j
  int r0 = bm + wm * 128 + ((l >> 4) << 2);
  int c0 = bn + wn * 64 + (l & 15);
#pragma unroll
  for (int nf = 0; nf < 4; ++nf) {
    float bv = bias[c0 + nf * 16];
#pragma unroll
    for (int mf = 0; mf < 8; ++mf) {
#pragma unroll
      for (int jj = 0; jj < 4; ++jj)
        C[(size_t)(r0 + mf * 16 + jj) * N_DIM + (c0 + nf * 16)] = acc[mf][nf][jj] + bv;
    }
  }
}

// ---------- naive fp32 fallback (only if ws_size too small) ----------
__global__ __launch_bounds__(256)
void gemm_naive(const float* __restrict__ A, const float* __restrict__ B,
                const float* __restrict__ bias, float* __restrict__ C) {
  __shared__ float As[64][17];
  __shared__ float Bs[16][65];
  int nbn = N_DIM / 64;
  int m0 = (blockIdx.x / nbn) * 64;
  int n0 = (blockIdx.x % nbn) * 64;
  int tid = threadIdx.x;
  int tx = tid & 15, ty = tid >> 4;
  float acc[4][4] = {};
  for (int k0 = 0; k0 < K_DIM; k0 += 16) {
    __syncthreads();
#pragma unroll
    for (int e = tid * 4, i = 0; i < 4; ++i) {
      int idx = e + i;
      int r = idx >> 4, k = idx & 15;
      As[r][k] = A[(size_t)(m0 + r) * K_DIM + k0 + k];
    }
#pragma unroll
    for (int e = tid * 4, i = 0; i < 4; ++i) {
      int idx = e + i;
      int k = idx >> 6, n = idx & 63;
      Bs[k][n] = B[(size_t)(k0 + k) * N_DIM + n0 + n];
    }
    __syncthreads();
#pragma unroll
    for (int kk = 0; kk < 16; ++kk)
#pragma unroll
      for (int i = 0; i < 4; ++i)
#pragma unroll
        for (int j = 0; j < 4; ++j)
          acc[i][j] += As[ty * 4 + i][kk] * Bs[kk][tx * 4 + j];
  }
#pragma unroll
  for (int i = 0; i < 4; ++i)
#pragma unroll
    for (int j = 0; j < 4; ++j) {
      int r = m0 + ty * 4 + i, c = n0 + tx * 4 + j;
      C[(size_t)r * N_DIM + c] = acc[i][j] + bias[c];
    }
}

extern "C" void kernel_launch(void* const* d_in, const int* in_sizes, int n_in,
                              void* d_out, int out_size, void* d_ws, size_t ws_size,
                              hipStream_t stream) {
  const float* A32  = (const float*)d_in[0];
  const float* W32  = (const float*)d_in[1];
  const float* bias = (const float*)d_in[2];
  float* C = (float*)d_out;

  const size_t needA = (size_t)M_TOTAL * K_DIM * sizeof(ushort_t); // 128 MiB
  const size_t needB = (size_t)N_DIM * K_DIM * sizeof(ushort_t);   // 32 MiB

  if (ws_size >= needA + needB) {
    ushort_t* Abf = (ushort_t*)d_ws;
    ushort_t* Btb = (ushort_t*)((char*)d_ws + needA);
    long n8 = (long)M_TOTAL * K_DIM / 8;
    cast_kernel<<<(int)((n8 + 255) / 256), 256, 0, stream>>>(A32, Abf, n8);
    transpose_cast_kernel<<<(K_DIM / 64) * (N_DIM / 64), 256, 0, stream>>>(W32, Btb);
    gemm_8phase<<<(M_TOTAL / BM) * (N_DIM / BN), 512, 0, stream>>>(Abf, Btb, bias, C);
  } else {
    gemm_naive<<<(M_TOTAL / 64) * (N_DIM / 64), 256, 0, stream>>>(A32, W32, bias, C);
  }
}

// Round 3
// 552.035 us; speedup vs baseline: 1.4858x; 1.0147x over previous
//
#include <hip/hip_runtime.h>
#include <hip/hip_bf16.h>
#include <cstdint>
#include <cstddef>

#define M_TOTAL 16384   // WORLD_SIZE * M_LOCAL
#define K_DIM   4096
#define N_DIM   4096

typedef __attribute__((ext_vector_type(8))) short s16x8;
typedef __attribute__((ext_vector_type(4))) float f32x4;
typedef unsigned short ushort_t;

// ---------- fp32 -> bf16 round-to-nearest-even ----------
__device__ __forceinline__ ushort_t f2bf(float x) {
  unsigned u = __float_as_uint(x);
  return (ushort_t)((u + 0x7fffu + ((u >> 16) & 1u)) >> 16);
}

// ---------- cast A [M,K] fp32 -> bf16, 8 elems/thread ----------
__global__ __launch_bounds__(256) void cast_kernel(const float* __restrict__ in,
                                                   ushort_t* __restrict__ out,
                                                   long n8) {
  long i = (long)blockIdx.x * 256 + threadIdx.x;
  if (i >= n8) return;
  const f32x4* p = (const f32x4*)in + i * 2;
  f32x4 a = p[0], b = p[1];
  union { s16x8 v; ushort_t u[8]; } r;
  r.u[0] = f2bf(a.x); r.u[1] = f2bf(a.y); r.u[2] = f2bf(a.z); r.u[3] = f2bf(a.w);
  r.u[4] = f2bf(b.x); r.u[5] = f2bf(b.y); r.u[6] = f2bf(b.z); r.u[7] = f2bf(b.w);
  *((s16x8*)out + i) = r.v;
}

// ---------- transpose+cast W [K,N] fp32 -> Bt [N,K] bf16 ----------
__global__ __launch_bounds__(256) void transpose_cast_kernel(const float* __restrict__ B,
                                                             ushort_t* __restrict__ Bt) {
  __shared__ float tile[64][65];
  int nbx = N_DIM / 64;
  int n0 = (blockIdx.x % nbx) * 64;
  int k0 = (blockIdx.x / nbx) * 64;
  int tx = threadIdx.x & 63;
  int ty = threadIdx.x >> 6;
#pragma unroll
  for (int i = 0; i < 64; i += 4)
    tile[ty + i][tx] = B[(size_t)(k0 + ty + i) * N_DIM + n0 + tx];
  __syncthreads();
#pragma unroll
  for (int i = 0; i < 64; i += 4)
    Bt[(size_t)(n0 + ty + i) * K_DIM + k0 + tx] = f2bf(tile[tx][ty + i]);
}

// ============================================================================
// 256x256 8-phase bf16 GEMM (T2 swizzle + T3/T4 counted vmcnt + T5 setprio)
// Round-3 changes vs round-2 (ledger IDENTICAL, pure scheduling):
//  (a) MFMA_Q loop order ks-outermost: 8 independent MFMAs between any
//      accumulator reuse (was dependent back-to-back pairs).
//  (b) vmcnt(4) drains in P4/P8 moved AFTER the MFMA cluster (data waited on
//      is only read after the closing barrier) -> ~80cy compute/drain overlap.
// Stage ledger (iteration j computes tiles 2j (buf0, P1-4), 2j+1 (buf1, P5-8)):
//   P1: t(2j+1) A-h0 -> buf1 | P2: A-h1 | P3: t(2j+2) B-h0 -> buf0
//   P4: B-h1; [MFMA]; vmcnt(4) drains t(2j+1)   (leaves P3,P4 in flight)
//   P5: t(2j+2) A-h0 -> buf0 | P6: A-h1 | P7: t(2j+3) B-h0 -> buf1
//   P8: B-h1; [MFMA]; vmcnt(4) drains t(2j+2)   (leaves P7,P8 in flight)
// Reads: Pc1: A-q0(8)+B-n0(4); Pc2: B-n1(4); Pc3: A-q1(8); Pc4: 0.
// ============================================================================
#define BM 256
#define BN 256
#define BK 64
#define NTILE (K_DIM / BK)   // 64 -> 32 iterations, last peeled

__device__ __forceinline__ void load_lds16(const ushort_t* g, ushort_t* l) {
  __builtin_amdgcn_global_load_lds(
      (const __attribute__((address_space(1))) unsigned int*)g,
      (__attribute__((address_space(3))) unsigned int*)l, 16, 0, 0);
}

#define BAR __builtin_amdgcn_s_barrier()
#define VMW4 asm volatile("s_waitcnt vmcnt(4)" ::: "memory")
#define VMW0 asm volatile("s_waitcnt vmcnt(0)" ::: "memory")

#define STAGE_A(dst, h, t) do { \
    load_lds16(pA + (size_t)((h) * 128) * K_DIM + (t) * 64, (dst) + (h) * 8192); \
    load_lds16(pA + (size_t)((h) * 128 + 64) * K_DIM + (t) * 64, (dst) + (h) * 8192 + 4096); } while (0)
#define STAGE_B(dst, h, t) do { \
    load_lds16(pB + (size_t)((h) * 128) * K_DIM + (t) * 64, (dst) + (h) * 8192); \
    load_lds16(pB + (size_t)((h) * 128 + 64) * K_DIM + (t) * 64, (dst) + (h) * 8192 + 4096); } while (0)

#define READ_A(buf, arr, q) do { \
    _Pragma("unroll") for (int mf = 0; mf < 4; ++mf) { \
      int ia = aBase + ((q) * 4 + mf) * 1024; \
      arr[mf][0] = *(const s16x8*)&lds[buf][ia]; \
      arr[mf][1] = *(const s16x8*)&lds[buf][ia ^ 32]; } } while (0)
#define READ_B(buf, arr, nh) do { \
    _Pragma("unroll") for (int nf = 0; nf < 2; ++nf) { \
      int ib = bBase + ((nh) * 2 + nf) * 1024; \
      arr[nf][0] = *(const s16x8*)&lds[buf][ib]; \
      arr[nf][1] = *(const s16x8*)&lds[buf][ib ^ 32]; } } while (0)

// ks OUTERMOST: consecutive MFMAs hit distinct accumulators (8 independent
// between reuse of the same acc) -> no dependent back-to-back MFMA stall.
#define MFMA_Q(arr_a, arr_b, m0, n0) do { \
    __builtin_amdgcn_s_setprio(1); \
    _Pragma("unroll") for (int ks = 0; ks < 2; ++ks) \
    _Pragma("unroll") for (int mf = 0; mf < 4; ++mf) \
    _Pragma("unroll") for (int nf = 0; nf < 2; ++nf) \
      acc[(m0) + mf][(n0) + nf] = __builtin_amdgcn_mfma_f32_16x16x32_bf16( \
          arr_a[mf][ks], arr_b[nf][ks], acc[(m0) + mf][(n0) + nf], 0, 0, 0); \
    __builtin_amdgcn_s_setprio(0); } while (0)

__global__ __launch_bounds__(512, 2)
void gemm_8phase(const ushort_t* __restrict__ A, const ushort_t* __restrict__ Bt,
                 const float* __restrict__ bias, float* __restrict__ C) {
  __shared__ ushort_t lds[2][32768];  // [buf][ A: 0..16383 | B: 16384..32767 ]

  // bijective XCD swizzle (nwg = 1024, % 8 == 0)
  int nwg = gridDim.x;
  int wg  = blockIdx.x;
  int swz = (wg & 7) * (nwg >> 3) + (wg >> 3);
  int bm = (swz >> 4) << 8;
  int bn = (swz & 15) << 8;

  int tid = threadIdx.x;
  int wid = tid >> 6;
  int l   = tid & 63;
  int wm = wid >> 2, wn = wid & 3;

  // staging: lane covers global (row = base + wid*8 + (l>>3), slot = (l&7)^(row&7))
  int sg8 = ((l & 7) ^ ((l >> 3) & 7)) << 3;
  const ushort_t* pA = A  + (size_t)(bm + wid * 8 + (l >> 3)) * K_DIM + sg8;
  const ushort_t* pB = Bt + (size_t)(bn + wid * 8 + (l >> 3)) * K_DIM + sg8;
  ushort_t* sA0 = &lds[0][wid * 512];
  ushort_t* sA1 = &lds[1][wid * 512];
  ushort_t* sB0 = &lds[0][16384 + wid * 512];
  ushort_t* sB1 = &lds[1][16384 + wid * 512];

  // read bases: row = (wm*128 | mf*16 | (l&15)); slot = (ks*4 | (l>>4)) ^ (l&7)
  int slot0 = (l >> 4) ^ (l & 7);
  int aBase = (wm * 128 + (l & 15)) * 64 + slot0 * 8;
  int bBase = 16384 + (wn * 64 + (l & 15)) * 64 + slot0 * 8;

  f32x4 acc[8][4];
#pragma unroll
  for (int mf = 0; mf < 8; ++mf)
#pragma unroll
    for (int nf = 0; nf < 4; ++nf) acc[mf][nf] = (f32x4){0.f, 0.f, 0.f, 0.f};

  s16x8 a[4][2], b0[2][2], b1[2][2];

  // prologue: tile0 full (8 issues), tile1 B halves (4 issues); drain tile0
  STAGE_B(sB0, 0, 0); STAGE_B(sB0, 1, 0);
  STAGE_A(sA0, 0, 0); STAGE_A(sA0, 1, 0);
  STAGE_B(sB1, 0, 1); STAGE_B(sB1, 1, 1);
  VMW4; BAR;

  for (int j = 0; j < NTILE / 2 - 1; ++j) {   // j = 0..30, tiles 0..61
    int t1 = 2 * j + 1, t2 = 2 * j + 2, t3 = 2 * j + 3;
    // P1
    READ_A(0, a, 0); READ_B(0, b0, 0);
    STAGE_A(sA1, 0, t1);
    BAR; MFMA_Q(a, b0, 0, 0); BAR;
    // P2
    READ_B(0, b1, 1);
    STAGE_A(sA1, 1, t1);
    BAR; MFMA_Q(a, b1, 0, 2); BAR;
    // P3
    READ_A(0, a, 1);
    STAGE_B(sB0, 0, t2);
    BAR; MFMA_Q(a, b1, 4, 2); BAR;
    // P4 (drain AFTER compute; buf1 reads only start past the closing BAR)
    STAGE_B(sB0, 1, t2);
    BAR; MFMA_Q(a, b0, 4, 0); VMW4; BAR;
    // P5
    READ_A(1, a, 0); READ_B(1, b0, 0);
    STAGE_A(sA0, 0, t2);
    BAR; MFMA_Q(a, b0, 0, 0); BAR;
    // P6
    READ_B(1, b1, 1);
    STAGE_A(sA0, 1, t2);
    BAR; MFMA_Q(a, b1, 0, 2); BAR;
    // P7
    READ_A(1, a, 1);
    STAGE_B(sB1, 0, t3);
    BAR; MFMA_Q(a, b1, 4, 2); BAR;
    // P8 (drain AFTER compute)
    STAGE_B(sB1, 1, t3);
    BAR; MFMA_Q(a, b0, 4, 0); VMW4; BAR;
  }

  // tail: tiles 62 (buf0), 63 (buf1); t63 A still staged at P1,P2
  {
    READ_A(0, a, 0); READ_B(0, b0, 0);
    STAGE_A(sA1, 0, 63);
    BAR; MFMA_Q(a, b0, 0, 0); BAR;

    READ_B(0, b1, 1);
    STAGE_A(sA1, 1, 63);
    BAR; MFMA_Q(a, b1, 0, 2); BAR;

    READ_A(0, a, 1);
    BAR; MFMA_Q(a, b1, 4, 2); BAR;

    BAR; MFMA_Q(a, b0, 4, 0); VMW0; BAR;   // t63 A+B fully landed

    READ_A(1, a, 0); READ_B(1, b0, 0);
    BAR; MFMA_Q(a, b0, 0, 0); BAR;

    READ_B(1, b1, 1);
    BAR; MFMA_Q(a, b1, 0, 2); BAR;

    READ_A(1, a, 1);
    BAR; MFMA_Q(a, b1, 4, 2); BAR;

    BAR; MFMA_Q(a, b0, 4, 0);
  }

  // epilogue: C/D layout col = lane&15, row = (lane>>4)*4 + j
  int r0 = bm + wm * 128 + ((l >> 4) << 2);
  int c0 = bn + wn * 64 + (l & 15);
#pragma unroll
  for (int nf = 0; nf < 4; ++nf) {
    float bv = bias[c0 + nf * 16];
#pragma unroll
    for (int mf = 0; mf < 8; ++mf) {
#pragma unroll
      for (int jj = 0; jj < 4; ++jj)
        C[(size_t)(r0 + mf * 16 + jj) * N_DIM + (c0 + nf * 16)] = acc[mf][nf][jj] + bv;
    }
  }
}

// ---------- naive fp32 fallback (only if ws_size too small) ----------
__global__ __launch_bounds__(256)
void gemm_naive(const float* __restrict__ A, const float* __restrict__ B,
                const float* __restrict__ bias, float* __restrict__ C) {
  __shared__ float As[64][17];
  __shared__ float Bs[16][65];
  int nbn = N_DIM / 64;
  int m0 = (blockIdx.x / nbn) * 64;
  int n0 = (blockIdx.x % nbn) * 64;
  int tid = threadIdx.x;
  int tx = tid & 15, ty = tid >> 4;
  float acc[4][4] = {};
  for (int k0 = 0; k0 < K_DIM; k0 += 16) {
    __syncthreads();
#pragma unroll
    for (int e = tid * 4, i = 0; i < 4; ++i) {
      int idx = e + i;
      int r = idx >> 4, k = idx & 15;
      As[r][k] = A[(size_t)(m0 + r) * K_DIM + k0 + k];
    }
#pragma unroll
    for (int e = tid * 4, i = 0; i < 4; ++i) {
      int idx = e + i;
      int k = idx >> 6, n = idx & 63;
      Bs[k][n] = B[(size_t)(k0 + k) * N_DIM + n0 + n];
    }
    __syncthreads();
#pragma unroll
    for (int kk = 0; kk < 16; ++kk)
#pragma unroll
      for (int i = 0; i < 4; ++i)
#pragma unroll
        for (int j = 0; j < 4; ++j)
          acc[i][j] += As[ty * 4 + i][kk] * Bs[kk][tx * 4 + j];
  }
#pragma unroll
  for (int i = 0; i < 4; ++i)
#pragma unroll
    for (int j = 0; j < 4; ++j) {
      int r = m0 + ty * 4 + i, c = n0 + tx * 4 + j;
      C[(size_t)r * N_DIM + c] = acc[i][j] + bias[c];
    }
}

extern "C" void kernel_launch(void* const* d_in, const int* in_sizes, int n_in,
                              void* d_out, int out_size, void* d_ws, size_t ws_size,
                              hipStream_t stream) {
  const float* A32  = (const float*)d_in[0];
  const float* W32  = (const float*)d_in[1];
  const float* bias = (const float*)d_in[2];
  float* C = (float*)d_out;

  const size_t needA = (size_t)M_TOTAL * K_DIM * sizeof(ushort_t); // 128 MiB
  const size_t needB = (size_t)N_DIM * K_DIM * sizeof(ushort_t);   // 32 MiB

  if (ws_size >= needA + needB) {
    ushort_t* Abf = (ushort_t*)d_ws;
    ushort_t* Btb = (ushort_t*)((char*)d_ws + needA);
    long n8 = (long)M_TOTAL * K_DIM / 8;
    cast_kernel<<<(int)((n8 + 255) / 256), 256, 0, stream>>>(A32, Abf, n8);
    transpose_cast_kernel<<<(K_DIM / 64) * (N_DIM / 64), 256, 0, stream>>>(W32, Btb);
    gemm_8phase<<<(M_TOTAL / BM) * (N_DIM / BN), 512, 0, stream>>>(Abf, Btb, bias, C);
  } else {
    gemm_naive<<<(M_TOTAL / 64) * (N_DIM / 64), 256, 0, stream>>>(A32, W32, bias, C);
  }
}